// Round 3
// baseline (241.598 us; speedup 1.0000x reference)
//
#include <hip/hip_runtime.h>
#include <hip/hip_bf16.h>
#include <float.h>

#define NF 75
#define HID 128
#define NB 50
#define NT 12
#define N_ATOMS_C 200000
#define BN_EPS 1e-3f
#define NSEG 64

// Static device scratch. Fully written before read on every launch.
__device__ float g_bn1[(size_t)N_ATOMS_C * HID];   // 102.4 MB
__device__ float g_part[NSEG * NB * 256];          // segment partials

struct AdjPtrs { const int* p[10]; };

__device__ __forceinline__ float fast_tanh(float x) {
    float e = __expf(2.f * x);
    return 1.f - 2.f / (e + 1.f);
}

// Degree layout (compile-time)
__device__ constexpr int DS_[12] = {0,1000,20000,60000,120000,170000,185000,193000,197000,199000,199700,200000};

// K=75 GEMM phase: acc[8][4] += A[64][75] @ W0[75][128] (W streamed from L1/L2)
__device__ __forceinline__ void gemm_phase(const float* __restrict__ A,
                                           const float* __restrict__ W0,
                                           float acc[8][4], int c0, int a0)
{
    for (int kb = 0; kb < 72; kb += 4) {
        const float4 w0 = *(const float4*)(W0 + (size_t)(kb + 0) * HID + c0);
        const float4 w1 = *(const float4*)(W0 + (size_t)(kb + 1) * HID + c0);
        const float4 w2 = *(const float4*)(W0 + (size_t)(kb + 2) * HID + c0);
        const float4 w3 = *(const float4*)(W0 + (size_t)(kb + 3) * HID + c0);
#pragma unroll
        for (int i = 0; i < 8; ++i) {
            const float4 av = *(const float4*)&A[(a0 + i) * 76 + kb];
            acc[i][0] = fmaf(av.w, w3.x, fmaf(av.z, w2.x, fmaf(av.y, w1.x, fmaf(av.x, w0.x, acc[i][0]))));
            acc[i][1] = fmaf(av.w, w3.y, fmaf(av.z, w2.y, fmaf(av.y, w1.y, fmaf(av.x, w0.y, acc[i][1]))));
            acc[i][2] = fmaf(av.w, w3.z, fmaf(av.z, w2.z, fmaf(av.y, w1.z, fmaf(av.x, w0.z, acc[i][2]))));
            acc[i][3] = fmaf(av.w, w3.w, fmaf(av.z, w2.w, fmaf(av.y, w1.w, fmaf(av.x, w0.w, acc[i][3]))));
        }
    }
#pragma unroll
    for (int kb = 72; kb < 75; ++kb) {
        const float4 w = *(const float4*)(W0 + (size_t)kb * HID + c0);
#pragma unroll
        for (int i = 0; i < 8; ++i) {
            const float av = A[(a0 + i) * 76 + kb];
            acc[i][0] = fmaf(av, w.x, acc[i][0]);
            acc[i][1] = fmaf(av, w.y, acc[i][1]);
            acc[i][2] = fmaf(av, w.z, acc[i][2]);
            acc[i][3] = fmaf(av, w.w, acc[i][3]);
        }
    }
}

// gc1 body: split-K (rel-phase then self-phase), A[64][76] f32 only.
template<int DEG>
__device__ __forceinline__ void gc1_body(
    int tile, float* __restrict__ A, int* __restrict__ S,
    const float* __restrict__ X, const float* __restrict__ W, const float* __restrict__ B,
    const float* __restrict__ bg, const float* __restrict__ bb,
    const float* __restrict__ bm, const float* __restrict__ bv,
    const int* __restrict__ adjBase)
{
    const int dStart = DS_[DEG], dEnd = DS_[DEG + 1];
    const int atom0  = dStart + tile * 64;
    const int nA     = min(64, dEnd - atom0);
    const int tid    = threadIdx.x;
    const float* __restrict__ Wrel = W + (size_t)(DEG > 0 ? 2 * (DEG - 1) : 0) * NF * HID;
    const float* __restrict__ Wslf = (DEG > 0) ? (Wrel + NF * HID) : (W + (size_t)20 * NF * HID);

    float acc[8][4] = {};
    const int c0 = (tid & 31) * 4;   // 4 consecutive cols
    const int a0 = (tid >> 5) * 8;   // 8 atoms

    if (DEG > 0) {
        // stash adjacency rows in LDS
        for (int idx = tid; idx < 64 * DEG; idx += 256) {
            const int a = idx / DEG, j = idx - a * DEG;
            S[a * DEG + j] = (a < nA) ? adjBase[(size_t)(atom0 + a - dStart) * DEG + j] : 0;
        }
        __syncthreads();
        // stage nbr_sum (scattered gather; f-major -> coalesced X reads)
        for (int idx = tid; idx < 64 * 76; idx += 256) {
            const int a = idx / 76, f = idx - a * 76;
            if (f < 75) {
                float nb = 0.f;
                if (a < nA) {
#pragma unroll
                    for (int j = 0; j < DEG; ++j) nb += X[(size_t)S[a * DEG + j] * NF + f];
                }
                A[a * 76 + f] = nb;
            }
        }
        __syncthreads();
        gemm_phase(A, Wrel, acc, c0, a0);
        __syncthreads();
    }
    // stage self (coalesced)
    for (int idx = tid; idx < 64 * 76; idx += 256) {
        const int a = idx / 76, f = idx - a * 76;
        if (f < 75) A[a * 76 + f] = (a < nA) ? X[(size_t)(atom0 + a) * NF + f] : 0.f;
    }
    __syncthreads();
    gemm_phase(A, Wslf, acc, c0, a0);

    // epilogue: +bias, tanh, batchnorm, store
    float bias[4], sc[4], sh[4];
#pragma unroll
    for (int j = 0; j < 4; ++j) {
        const int c = c0 + j;
        float bsum;
        if (DEG > 0) {
            const float* br = B + 2 * (DEG - 1) * HID;
            bsum = br[c] + br[HID + c];
        } else {
            bsum = B[20 * HID + c];
        }
        bias[j] = bsum;
        const float s = bg[c] * rsqrtf(bv[c] + BN_EPS);
        sc[j] = s;
        sh[j] = bb[c] - bm[c] * s;
    }
#pragma unroll
    for (int i = 0; i < 8; ++i) {
        if (a0 + i < nA) {
            float4 r;
            r.x = fast_tanh(acc[i][0] + bias[0]) * sc[0] + sh[0];
            r.y = fast_tanh(acc[i][1] + bias[1]) * sc[1] + sh[1];
            r.z = fast_tanh(acc[i][2] + bias[2]) * sc[2] + sh[2];
            r.w = fast_tanh(acc[i][3] + bias[3]) * sc[3] + sh[3];
            *(float4*)&g_bn1[(size_t)(atom0 + a0 + i) * HID + c0] = r;
        }
    }
}

__global__ __launch_bounds__(256, 8) void k_gc1(
    const float* __restrict__ X, const float* __restrict__ W, const float* __restrict__ B,
    const float* __restrict__ bg, const float* __restrict__ bb,
    const float* __restrict__ bm, const float* __restrict__ bv,
    AdjPtrs adj)
{
    constexpr int TS[12] = {0,16,313,938,1876,2658,2893,3018,3081,3113,3124,3129};
    __shared__ __align__(16) float A[64 * 76];   // 19.5 KB
    __shared__ int S[64 * 10];                   // 2.5 KB  -> 7 blocks/CU

    const int blk = blockIdx.x;
    int deg = 0;
#pragma unroll
    for (int d = 1; d <= 10; ++d) if (blk >= TS[d]) deg = d;
    const int tile = blk - TS[deg];

    switch (deg) {
        case 0:  gc1_body<0 >(tile, A, S, X, W, B, bg, bb, bm, bv, nullptr);   break;
        case 1:  gc1_body<1 >(tile, A, S, X, W, B, bg, bb, bm, bv, adj.p[0]);  break;
        case 2:  gc1_body<2 >(tile, A, S, X, W, B, bg, bb, bm, bv, adj.p[1]);  break;
        case 3:  gc1_body<3 >(tile, A, S, X, W, B, bg, bb, bm, bv, adj.p[2]);  break;
        case 4:  gc1_body<4 >(tile, A, S, X, W, B, bg, bb, bm, bv, adj.p[3]);  break;
        case 5:  gc1_body<5 >(tile, A, S, X, W, B, bg, bb, bm, bv, adj.p[4]);  break;
        case 6:  gc1_body<6 >(tile, A, S, X, W, B, bg, bb, bm, bv, adj.p[5]);  break;
        case 7:  gc1_body<7 >(tile, A, S, X, W, B, bg, bb, bm, bv, adj.p[6]);  break;
        case 8:  gc1_body<8 >(tile, A, S, X, W, B, bg, bb, bm, bv, adj.p[7]);  break;
        case 9:  gc1_body<9 >(tile, A, S, X, W, B, bg, bb, bm, bv, adj.p[8]);  break;
        case 10: gc1_body<10>(tile, A, S, X, W, B, bg, bb, bm, bv, adj.p[9]);  break;
    }
}

// ---------------- K2: deterministic segment sum/max partials ----------------
// Block = (stripe s in 0..NSEG-1) x (batch b); 2 waves build per-wave queues
// via ballot compaction (deterministic), then 128 col-threads reduce.
__global__ __launch_bounds__(128) void k_seg(const int* __restrict__ memb)
{
    const int b = blockIdx.x % NB;
    const int s = blockIdx.x / NB;
    const int aLo = s * (N_ATOMS_C / NSEG);
    const int aHi = aLo + (N_ATOMS_C / NSEG);
    const int wave = threadIdx.x >> 6;
    const int lane = threadIdx.x & 63;

    __shared__ int q[2][256];
    __shared__ int qn[2];
    int* myq = q[wave];
    int nq = 0;

    for (int base = aLo + wave * 64; base < aHi; base += 128) {
        const int a = base + lane;
        const bool m = (a < aHi) && (memb[a] == b);
        const unsigned long long bal = __ballot(m);
        if (m) {
            const int pos = __popcll(bal & ((1ull << lane) - 1ull));
            if (nq + pos < 256) myq[nq + pos] = a;
        }
        nq += __popcll(bal);
    }
    if (lane == 0) qn[wave] = min(nq, 256);
    __syncthreads();

    const int c = threadIdx.x;  // col 0..127
    float sum = 0.f, mx = -FLT_MAX;
#pragma unroll
    for (int w2 = 0; w2 < 2; ++w2) {
        const int n = qn[w2];
        for (int i = 0; i < n; ++i) {
            const float v = g_bn1[(size_t)q[w2][i] * HID + c];
            sum += v;
            mx = fmaxf(mx, v);
        }
    }
    float* pd = g_part + (size_t)(s * NB + b) * 256;
    pd[c] = sum;
    pd[128 + c] = mx;
}

// ---------------- K3: reduce partials, tanh, dense [256,24], softmax pairs ----------------
__global__ __launch_bounds__(256) void k_final(const float* __restrict__ W2,
                                               const float* __restrict__ b2,
                                               float* __restrict__ out)
{
    const int b = blockIdx.x;
    const int t = threadIdx.x;
    __shared__ float ro[256];
    __shared__ float lg[24];

    {
        float v;
        if (t < 128) {
            float sv = 0.f;
            for (int s = 0; s < NSEG; ++s) sv += g_part[(size_t)(s * NB + b) * 256 + t];
            v = sv;
        } else {
            float mv = -FLT_MAX;
            for (int s = 0; s < NSEG; ++s) mv = fmaxf(mv, g_part[(size_t)(s * NB + b) * 256 + t]);
            v = mv;
        }
        ro[t] = tanhf(v);
    }
    __syncthreads();
    if (t < 24) {
        float acc = b2[t];
        for (int c = 0; c < 256; ++c) acc = fmaf(ro[c], W2[c * 24 + t], acc);
        lg[t] = acc;
    }
    __syncthreads();
    if (t < NT) {
        const float l0 = lg[2 * t], l1 = lg[2 * t + 1];
        const float m = fmaxf(l0, l1);
        const float e0 = expf(l0 - m), e1 = expf(l1 - m);
        const float inv = 1.f / (e0 + e1);
        out[b * 24 + 2 * t]     = e0 * inv;
        out[b * 24 + 2 * t + 1] = e1 * inv;
    }
}

extern "C" void kernel_launch(void* const* d_in, const int* in_sizes, int n_in,
                              void* d_out, int out_size, void* d_ws, size_t ws_size,
                              hipStream_t stream) {
    const float* X    = (const float*)d_in[0];
    const int*   memb = (const int*)d_in[2];
    AdjPtrs adj;
    for (int d = 0; d < 10; ++d) adj.p[d] = (const int*)d_in[3 + d];
    const float* W1 = (const float*)d_in[13];
    const float* B1 = (const float*)d_in[14];
    const float* bg = (const float*)d_in[17];
    const float* bb = (const float*)d_in[18];
    const float* bm = (const float*)d_in[19];
    const float* bv = (const float*)d_in[20];
    const float* W2 = (const float*)d_in[31];
    const float* b2 = (const float*)d_in[32];
    float* out = (float*)d_out;

    k_gc1<<<3129, 256, 0, stream>>>(X, W1, B1, bg, bb, bm, bv, adj);
    k_seg<<<NSEG * NB, 128, 0, stream>>>(memb);
    k_final<<<NB, 256, 0, stream>>>(W2, b2, out);
}

// Round 4
// 221.775 us; speedup vs baseline: 1.0894x; 1.0894x over previous
//
#include <hip/hip_runtime.h>
#include <hip/hip_bf16.h>
#include <float.h>

#define NF 75
#define HID 128
#define NB 50
#define NT 12
#define BN_EPS 1e-3f
#define NSEG 64

typedef __attribute__((ext_vector_type(8))) short short8;
typedef __attribute__((ext_vector_type(4))) float f32x4;

// Static device scratch. Fully written before read on every launch.
__device__ float g_bn1[(size_t)200000 * HID];          // 102.4 MB
__device__ float g_part[NSEG * NB * 256];              // segment partials
__device__ unsigned short g_wfrag[11 * 5 * 8 * 64 * 16]; // frag-ordered W, hi/lo bf16 (901 KB)

struct AdjPtrs { const int* p[10]; };

__device__ __forceinline__ unsigned short f2bf(float x) {
    union { float f; unsigned u; } a; a.f = x;
    unsigned r = a.u + 0x7fffu + ((a.u >> 16) & 1u);   // RTNE
    return (unsigned short)(r >> 16);
}
__device__ __forceinline__ float bf2f(unsigned short h) {
    union { unsigned u; float f; } a; a.u = ((unsigned)h) << 16; return a.f;
}
__device__ __forceinline__ float fast_tanh(float x) {
    float e = __expf(2.f * x);
    return 1.f - 2.f / (e + 1.f);
}

// Degree layout (compile-time)
__device__ constexpr int DS_[12] = {0,1000,20000,60000,120000,170000,185000,193000,197000,199000,199700,200000};

// XOR-swizzled byte address inside the A-tile LDS buffer ([64 rows][128 B/row]).
// Row = atom-local index; byteInRow = g*32 + h*16 + off (g=k-group, h=0 hi / 1 lo).
__device__ __forceinline__ int swzb(int row, int byteInRow) {
    return row * 128 + (byteInRow ^ ((row & 7) << 4));
}

// ---------------- K0: W -> fragment-ordered bf16 hi/lo ----------------
// Kcat layout per degree: k in [0,75) = rel W rows, [80,155) = self W rows, else 0.
// deg 0: rel region all-zero, self = W[20]. Frag: lane l holds col=nt*16+(l&15),
// k = kt*32+(l>>4)*8+i  (i=0..7), hi[0..7] then lo[0..7].
__global__ __launch_bounds__(64) void k_wconv(const float* __restrict__ W) {
    const int id = blockIdx.x;                 // deg*40 + kt*8 + nt
    const int deg = id / 40, kt = (id / 8) % 5, nt = id % 8;
    const int lane = threadIdx.x;
    const int c  = nt * 16 + (lane & 15);
    const int kb = kt * 32 + (lane >> 4) * 8;
    unsigned short hs[8], ls[8];
#pragma unroll
    for (int i = 0; i < 8; ++i) {
        const int k = kb + i;
        float v = 0.f;
        if (deg > 0) {
            if (k < 75)              v = W[(size_t)(2 * (deg - 1)) * NF * HID + (size_t)k * HID + c];
            else if (k >= 80 && k < 155) v = W[(size_t)(2 * (deg - 1) + 1) * NF * HID + (size_t)(k - 80) * HID + c];
        } else {
            if (k >= 80 && k < 155)  v = W[(size_t)20 * NF * HID + (size_t)(k - 80) * HID + c];
        }
        const unsigned short h = f2bf(v);
        hs[i] = h;
        ls[i] = f2bf(v - bf2f(h));
    }
    unsigned short* dst = g_wfrag + ((size_t)id * 64 + lane) * 16;
#pragma unroll
    for (int i = 0; i < 8; ++i) { dst[i] = hs[i]; dst[8 + i] = ls[i]; }
}

// ---------------- K1: gc1 via MFMA (bf16 hi/lo 3-term) + tanh + bn1 ----------------
// 512 threads = 8 waves. Wave w owns N-tile w (16 cols) x all 64 atoms.
// A staged per K-step (32 k) into LDS as bf16 hi/lo, double-buffered, swizzled.
template<int DEG>
__device__ __forceinline__ void gc1_body(
    int tile, char* Ab0, char* Ab1, int* S,
    const float* __restrict__ X, const float* __restrict__ B,
    const float* __restrict__ bg, const float* __restrict__ bb,
    const float* __restrict__ bm, const float* __restrict__ bv,
    const int* __restrict__ adjBase)
{
    const int dStart = DS_[DEG], dEnd = DS_[DEG + 1];
    const int atom0  = dStart + tile * 64;
    const int nA     = min(64, dEnd - atom0);
    const int tid    = threadIdx.x;
    const int lane   = tid & 63;
    const int wid    = tid >> 6;      // N-tile 0..7

    // adj stash into LDS
    if (DEG > 0) {
        for (int idx = tid; idx < 64 * DEG; idx += 512) {
            const int a = idx / DEG;
            S[idx] = (a < nA) ? adjBase[(size_t)(atom0 + a - dStart) * DEG + (idx - a * DEG)] : 0;
        }
        __syncthreads();
    }

    // staging role: thread -> (row, kq); kq*4 = k-offset within the 32-wide K-step
    const int srow = tid & 63;
    const int skq  = tid >> 6;        // 0..7

    f32x4 acc[4] = {};
    char* bufs[2] = {Ab0, Ab1};
    const int kt0 = (DEG == 0) ? 2 : 0;

    // --- stage one K-step: gather -> v[4] f32 ---
    auto stage_load = [&](int kt, float v[4]) {
        const int k0 = kt * 32 + skq * 4;
#pragma unroll
        for (int ii = 0; ii < 4; ++ii) v[ii] = 0.f;
        if (srow < nA) {
            if (k0 < 80) {
                if (DEG > 0) {
#pragma unroll
                    for (int j = 0; j < DEG; ++j) {
                        const float* xp = X + (size_t)S[srow * DEG + j] * NF + k0;
#pragma unroll
                        for (int ii = 0; ii < 4; ++ii)
                            if (k0 + ii < 75) v[ii] += xp[ii];
                    }
                }
            } else {
                const int f0 = k0 - 80;
                const float* xp = X + (size_t)(atom0 + srow) * NF + f0;
#pragma unroll
                for (int ii = 0; ii < 4; ++ii)
                    if (f0 + ii < 75) v[ii] = xp[ii];
            }
        }
    };
    // --- cvt hi/lo + LDS write (8B hi, 8B lo) ---
    auto stage_store = [&](const float v[4], char* buf) {
        unsigned long long hp = 0, lp = 0;
#pragma unroll
        for (int ii = 0; ii < 4; ++ii) {
            const unsigned short h = f2bf(v[ii]);
            const unsigned short l = f2bf(v[ii] - bf2f(h));
            hp |= (unsigned long long)h << (16 * ii);
            lp |= (unsigned long long)l << (16 * ii);
        }
        const int g = skq >> 1, half = skq & 1;
        *(unsigned long long*)(buf + swzb(srow, g * 32 + half * 8))      = hp;
        *(unsigned long long*)(buf + swzb(srow, g * 32 + 16 + half * 8)) = lp;
    };

    { float v[4]; stage_load(kt0, v); stage_store(v, bufs[kt0 & 1]); }
    __syncthreads();

    for (int kt = kt0; kt < 5; ++kt) {
        char* cur = bufs[kt & 1];
        const bool more = (kt + 1 < 5);
        float v[4];
        if (more) stage_load(kt + 1, v);            // issue gathers early (T14)

        const unsigned short* wp = g_wfrag + ((size_t)(((DEG * 5 + kt) * 8 + wid) * 64 + lane)) * 16;
        const short8 wh = *(const short8*)wp;
        const short8 wl = *(const short8*)(wp + 8);
        const int g = lane >> 4;
#pragma unroll
        for (int m = 0; m < 4; ++m) {
            const int r = m * 16 + (lane & 15);
            const short8 ah = *(const short8*)(cur + swzb(r, g * 32));
            const short8 al = *(const short8*)(cur + swzb(r, g * 32 + 16));
            acc[m] = __builtin_amdgcn_mfma_f32_16x16x32_bf16(ah, wh, acc[m], 0, 0, 0);
            acc[m] = __builtin_amdgcn_mfma_f32_16x16x32_bf16(al, wh, acc[m], 0, 0, 0);
            acc[m] = __builtin_amdgcn_mfma_f32_16x16x32_bf16(ah, wl, acc[m], 0, 0, 0);
        }
        if (more) stage_store(v, bufs[(kt + 1) & 1]);
        __syncthreads();
    }

    // epilogue: +bias, tanh, batchnorm, store (col fixed per lane)
    const int col = wid * 16 + (lane & 15);
    const float bsum = (DEG > 0)
        ? (B[(size_t)(2 * (DEG - 1)) * HID + col] + B[(size_t)(2 * (DEG - 1) + 1) * HID + col])
        : B[(size_t)20 * HID + col];
    const float s  = bg[col] * rsqrtf(bv[col] + BN_EPS);
    const float sh = bb[col] - bm[col] * s;
#pragma unroll
    for (int m = 0; m < 4; ++m) {
#pragma unroll
        for (int j = 0; j < 4; ++j) {
            const int r = m * 16 + (lane >> 4) * 4 + j;
            if (r < nA)
                g_bn1[(size_t)(atom0 + r) * HID + col] = fast_tanh(acc[m][j] + bsum) * s + sh;
        }
    }
}

__global__ __launch_bounds__(512, 8) void k_gc1(
    const float* __restrict__ X, const float* __restrict__ B,
    const float* __restrict__ bg, const float* __restrict__ bb,
    const float* __restrict__ bm, const float* __restrict__ bv,
    AdjPtrs adj)
{
    constexpr int TS[12] = {0,16,313,938,1876,2658,2893,3018,3081,3113,3124,3129};
    __shared__ __align__(16) char Ab0[8192];
    __shared__ __align__(16) char Ab1[8192];
    __shared__ int S[64 * 10];

    const int blk = blockIdx.x;
    int deg = 0;
#pragma unroll
    for (int d = 1; d <= 10; ++d) if (blk >= TS[d]) deg = d;
    const int tile = blk - TS[deg];

    switch (deg) {
        case 0:  gc1_body<0 >(tile, Ab0, Ab1, S, X, B, bg, bb, bm, bv, nullptr);   break;
        case 1:  gc1_body<1 >(tile, Ab0, Ab1, S, X, B, bg, bb, bm, bv, adj.p[0]);  break;
        case 2:  gc1_body<2 >(tile, Ab0, Ab1, S, X, B, bg, bb, bm, bv, adj.p[1]);  break;
        case 3:  gc1_body<3 >(tile, Ab0, Ab1, S, X, B, bg, bb, bm, bv, adj.p[2]);  break;
        case 4:  gc1_body<4 >(tile, Ab0, Ab1, S, X, B, bg, bb, bm, bv, adj.p[3]);  break;
        case 5:  gc1_body<5 >(tile, Ab0, Ab1, S, X, B, bg, bb, bm, bv, adj.p[4]);  break;
        case 6:  gc1_body<6 >(tile, Ab0, Ab1, S, X, B, bg, bb, bm, bv, adj.p[5]);  break;
        case 7:  gc1_body<7 >(tile, Ab0, Ab1, S, X, B, bg, bb, bm, bv, adj.p[6]);  break;
        case 8:  gc1_body<8 >(tile, Ab0, Ab1, S, X, B, bg, bb, bm, bv, adj.p[7]);  break;
        case 9:  gc1_body<9 >(tile, Ab0, Ab1, S, X, B, bg, bb, bm, bv, adj.p[8]);  break;
        case 10: gc1_body<10>(tile, Ab0, Ab1, S, X, B, bg, bb, bm, bv, adj.p[9]);  break;
    }
}

// ---------------- K2: deterministic segment sum/max partials ----------------
__global__ __launch_bounds__(128) void k_seg(const int* __restrict__ memb)
{
    const int b = blockIdx.x % NB;
    const int s = blockIdx.x / NB;
    const int aLo = s * (200000 / NSEG);
    const int aHi = aLo + (200000 / NSEG);
    const int wave = threadIdx.x >> 6;
    const int lane = threadIdx.x & 63;

    __shared__ int q[2][256];
    __shared__ int qn[2];
    int* myq = q[wave];
    int nq = 0;

    for (int base = aLo + wave * 64; base < aHi; base += 128) {
        const int a = base + lane;
        const bool m = (a < aHi) && (memb[a] == b);
        const unsigned long long bal = __ballot(m);
        if (m) {
            const int pos = __popcll(bal & ((1ull << lane) - 1ull));
            if (nq + pos < 256) myq[nq + pos] = a;
        }
        nq += __popcll(bal);
    }
    if (lane == 0) qn[wave] = min(nq, 256);
    __syncthreads();

    const int c = threadIdx.x;  // col 0..127
    float sum = 0.f, mx = -FLT_MAX;
#pragma unroll
    for (int w2 = 0; w2 < 2; ++w2) {
        const int n = qn[w2];
        for (int i = 0; i < n; ++i) {
            const float v = g_bn1[(size_t)q[w2][i] * HID + c];
            sum += v;
            mx = fmaxf(mx, v);
        }
    }
    float* pd = g_part + (size_t)(s * NB + b) * 256;
    pd[c] = sum;
    pd[128 + c] = mx;
}

// ---------------- K3: reduce partials, tanh, dense [256,24], softmax pairs ----------------
__global__ __launch_bounds__(256) void k_final(const float* __restrict__ W2,
                                               const float* __restrict__ b2,
                                               float* __restrict__ out)
{
    const int b = blockIdx.x;
    const int t = threadIdx.x;
    __shared__ float ro[256];
    __shared__ float lg[24];

    {
        float v;
        if (t < 128) {
            float sv = 0.f;
            for (int s = 0; s < NSEG; ++s) sv += g_part[(size_t)(s * NB + b) * 256 + t];
            v = sv;
        } else {
            float mv = -FLT_MAX;
            for (int s = 0; s < NSEG; ++s) mv = fmaxf(mv, g_part[(size_t)(s * NB + b) * 256 + t]);
            v = mv;
        }
        ro[t] = tanhf(v);
    }
    __syncthreads();
    if (t < 24) {
        float acc = b2[t];
        for (int c = 0; c < 256; ++c) acc = fmaf(ro[c], W2[c * 24 + t], acc);
        lg[t] = acc;
    }
    __syncthreads();
    if (t < NT) {
        const float l0 = lg[2 * t], l1 = lg[2 * t + 1];
        const float m = fmaxf(l0, l1);
        const float e0 = expf(l0 - m), e1 = expf(l1 - m);
        const float inv = 1.f / (e0 + e1);
        out[b * 24 + 2 * t]     = e0 * inv;
        out[b * 24 + 2 * t + 1] = e1 * inv;
    }
}

extern "C" void kernel_launch(void* const* d_in, const int* in_sizes, int n_in,
                              void* d_out, int out_size, void* d_ws, size_t ws_size,
                              hipStream_t stream) {
    const float* X    = (const float*)d_in[0];
    const int*   memb = (const int*)d_in[2];
    AdjPtrs adj;
    for (int d = 0; d < 10; ++d) adj.p[d] = (const int*)d_in[3 + d];
    const float* W1 = (const float*)d_in[13];
    const float* B1 = (const float*)d_in[14];
    const float* bg = (const float*)d_in[17];
    const float* bb = (const float*)d_in[18];
    const float* bm = (const float*)d_in[19];
    const float* bv = (const float*)d_in[20];
    const float* W2 = (const float*)d_in[31];
    const float* b2 = (const float*)d_in[32];
    float* out = (float*)d_out;

    k_wconv<<<440, 64, 0, stream>>>(W1);
    k_gc1<<<3129, 512, 0, stream>>>(X, B1, bg, bb, bm, bv, adj);
    k_seg<<<NSEG * NB, 128, 0, stream>>>(memb);
    k_final<<<NB, 256, 0, stream>>>(W2, b2, out);
}

// Round 5
// 184.677 us; speedup vs baseline: 1.3082x; 1.2009x over previous
//
#include <hip/hip_runtime.h>
#include <hip/hip_bf16.h>
#include <float.h>

#define NF 75
#define HID 128
#define NB 50
#define NT 12
#define BN_EPS 1e-3f
#define NSEG 64

typedef __attribute__((ext_vector_type(8))) short short8;
typedef __attribute__((ext_vector_type(4))) float f32x4;

// Static device scratch. Fully written before read on every launch.
__device__ float g_bn1[(size_t)200000 * HID];            // 102.4 MB
__device__ float g_xp[(size_t)200000 * 80];              // padded X, 64 MB
__device__ float g_part[NSEG * NB * 256];                // segment partials
__device__ unsigned short g_wfrag[11 * 5 * 8 * 64 * 16]; // frag-ordered W, hi/lo bf16

struct AdjPtrs { const int* p[10]; };

__device__ __forceinline__ unsigned short f2bf(float x) {
    union { float f; unsigned u; } a; a.f = x;
    unsigned r = a.u + 0x7fffu + ((a.u >> 16) & 1u);   // RTNE
    return (unsigned short)(r >> 16);
}
__device__ __forceinline__ float bf2f(unsigned short h) {
    union { unsigned u; float f; } a; a.u = ((unsigned)h) << 16; return a.f;
}
__device__ __forceinline__ float fast_tanh(float x) {
    float e = __expf(2.f * x);
    return 1.f - 2.f / (e + 1.f);
}

__device__ constexpr int DS_[12] = {0,1000,20000,60000,120000,170000,185000,193000,197000,199000,199700,200000};

// XOR-swizzled byte address inside an A-tile LDS buffer ([64 rows][128 B/row]).
__device__ __forceinline__ int swzb(int row, int byteInRow) {
    return row * 128 + (byteInRow ^ ((row & 7) << 4));
}

// ---------------- K_xpad: X[200000][75] -> g_xp[200000][80], zero-padded ----------------
// 3125 blocks x 64 rows. Both global streams are aligned float4.
__global__ __launch_bounds__(256) void k_xpad(const float* __restrict__ X) {
    __shared__ float T[64 * 75];
    const float4* src = (const float4*)(X + (size_t)blockIdx.x * 4800);
    for (int i = threadIdx.x; i < 1200; i += 256)
        *(float4*)&T[i * 4] = src[i];
    __syncthreads();
    float4* dst = (float4*)(g_xp + (size_t)blockIdx.x * 5120);
    for (int o = threadIdx.x; o < 1280; o += 256) {
        const int row = o / 20, f0 = (o % 20) * 4;
        float4 r;
        r.x = (f0 + 0 < 75) ? T[row * 75 + f0 + 0] : 0.f;
        r.y = (f0 + 1 < 75) ? T[row * 75 + f0 + 1] : 0.f;
        r.z = (f0 + 2 < 75) ? T[row * 75 + f0 + 2] : 0.f;
        r.w = (f0 + 3 < 75) ? T[row * 75 + f0 + 3] : 0.f;
        dst[o] = r;
    }
}

// ---------------- K0: W -> fragment-ordered bf16 hi/lo (unchanged from R4) ----------------
__global__ __launch_bounds__(64) void k_wconv(const float* __restrict__ W) {
    const int id = blockIdx.x;                 // deg*40 + kt*8 + nt
    const int deg = id / 40, kt = (id / 8) % 5, nt = id % 8;
    const int lane = threadIdx.x;
    const int c  = nt * 16 + (lane & 15);
    const int kb = kt * 32 + (lane >> 4) * 8;
    unsigned short hs[8], ls[8];
#pragma unroll
    for (int i = 0; i < 8; ++i) {
        const int k = kb + i;
        float v = 0.f;
        if (deg > 0) {
            if (k < 75)                  v = W[(size_t)(2 * (deg - 1)) * NF * HID + (size_t)k * HID + c];
            else if (k >= 80 && k < 155) v = W[(size_t)(2 * (deg - 1) + 1) * NF * HID + (size_t)(k - 80) * HID + c];
        } else {
            if (k >= 80 && k < 155)      v = W[(size_t)20 * NF * HID + (size_t)(k - 80) * HID + c];
        }
        const unsigned short h = f2bf(v);
        hs[i] = h;
        ls[i] = f2bf(v - bf2f(h));
    }
    unsigned short* dst = g_wfrag + ((size_t)id * 64 + lane) * 16;
#pragma unroll
    for (int i = 0; i < 8; ++i) { dst[i] = hs[i]; dst[8 + i] = ls[i]; }
}

// ---------------- K1: gc1 via MFMA, float4 gather from padded g_xp ----------------
// 512 threads = 8 waves. Wave w owns N-tile w (16 cols) x all 64 atoms, and
// stages chunk q=w (4 k-values per lane-row) -> wave-uniform staging branches.
template<int DEG>
__device__ __forceinline__ void gc1_body(
    int tile, char* Ab0, char* Ab1, int* S,
    const float* __restrict__ B,
    const float* __restrict__ bg, const float* __restrict__ bb,
    const float* __restrict__ bm, const float* __restrict__ bv,
    const int* __restrict__ adjBase)
{
    const int dStart = DS_[DEG], dEnd = DS_[DEG + 1];
    const int atom0  = dStart + tile * 64;
    const int nA     = min(64, dEnd - atom0);
    const int tid    = threadIdx.x;
    const int lane   = tid & 63;
    const int wid    = tid >> 6;      // N-tile AND staging chunk

    if (DEG > 0) {
        for (int idx = tid; idx < 64 * DEG; idx += 512) {
            const int a = idx / DEG;
            S[idx] = (a < nA) ? adjBase[(size_t)(atom0 + a - dStart) * DEG + (idx - a * DEG)] : 0;
        }
        __syncthreads();
    }

    const int srow = lane;            // staged row

    f32x4 acc[4] = {};
    char* bufs[2] = {Ab0, Ab1};
    const int kt0 = (DEG == 0) ? 2 : 0;

    auto stage_load = [&](int kt, float4& v) {
        const int k0 = kt * 32 + wid * 4;
        v.x = v.y = v.z = v.w = 0.f;
        if (srow < nA) {
            if (k0 < 80) {
                if (DEG > 0) {
#pragma unroll
                    for (int j = 0; j < DEG; ++j) {
                        const float4 t = *(const float4*)(g_xp + (size_t)S[srow * DEG + j] * 80 + k0);
                        v.x += t.x; v.y += t.y; v.z += t.z; v.w += t.w;
                    }
                }
            } else {
                v = *(const float4*)(g_xp + (size_t)(atom0 + srow) * 80 + (k0 - 80));
            }
        }
    };
    auto stage_store = [&](const float4 v, char* buf) {
        const float vv[4] = {v.x, v.y, v.z, v.w};
        unsigned long long hp = 0, lp = 0;
#pragma unroll
        for (int ii = 0; ii < 4; ++ii) {
            const unsigned short h = f2bf(vv[ii]);
            const unsigned short l = f2bf(vv[ii] - bf2f(h));
            hp |= (unsigned long long)h << (16 * ii);
            lp |= (unsigned long long)l << (16 * ii);
        }
        const int g = wid >> 1, half = wid & 1;
        *(unsigned long long*)(buf + swzb(srow, g * 32 + half * 8))      = hp;
        *(unsigned long long*)(buf + swzb(srow, g * 32 + 16 + half * 8)) = lp;
    };

    { float4 v; stage_load(kt0, v); stage_store(v, bufs[kt0 & 1]); }
    __syncthreads();

    for (int kt = kt0; kt < 5; ++kt) {
        char* cur = bufs[kt & 1];
        const bool more = (kt + 1 < 5);
        float4 v;
        if (more) stage_load(kt + 1, v);            // issue gathers early (T14)

        const unsigned short* wp = g_wfrag + ((size_t)(((DEG * 5 + kt) * 8 + wid) * 64 + lane)) * 16;
        const short8 wh = *(const short8*)wp;
        const short8 wl = *(const short8*)(wp + 8);
        const int g = lane >> 4;
#pragma unroll
        for (int m = 0; m < 4; ++m) {
            const int r = m * 16 + (lane & 15);
            const short8 ah = *(const short8*)(cur + swzb(r, g * 32));
            const short8 al = *(const short8*)(cur + swzb(r, g * 32 + 16));
            acc[m] = __builtin_amdgcn_mfma_f32_16x16x32_bf16(ah, wh, acc[m], 0, 0, 0);
            acc[m] = __builtin_amdgcn_mfma_f32_16x16x32_bf16(al, wh, acc[m], 0, 0, 0);
            acc[m] = __builtin_amdgcn_mfma_f32_16x16x32_bf16(ah, wl, acc[m], 0, 0, 0);
        }
        if (more) stage_store(v, bufs[(kt + 1) & 1]);
        __syncthreads();
    }

    const int col = wid * 16 + (lane & 15);
    const float bsum = (DEG > 0)
        ? (B[(size_t)(2 * (DEG - 1)) * HID + col] + B[(size_t)(2 * (DEG - 1) + 1) * HID + col])
        : B[(size_t)20 * HID + col];
    const float s  = bg[col] * rsqrtf(bv[col] + BN_EPS);
    const float sh = bb[col] - bm[col] * s;
#pragma unroll
    for (int m = 0; m < 4; ++m) {
#pragma unroll
        for (int j = 0; j < 4; ++j) {
            const int r = m * 16 + (lane >> 4) * 4 + j;
            if (r < nA)
                g_bn1[(size_t)(atom0 + r) * HID + col] = fast_tanh(acc[m][j] + bsum) * s + sh;
        }
    }
}

__global__ __launch_bounds__(512, 4) void k_gc1(
    const float* __restrict__ B,
    const float* __restrict__ bg, const float* __restrict__ bb,
    const float* __restrict__ bm, const float* __restrict__ bv,
    AdjPtrs adj)
{
    constexpr int TS[12] = {0,16,313,938,1876,2658,2893,3018,3081,3113,3124,3129};
    __shared__ __align__(16) char Ab0[8192];
    __shared__ __align__(16) char Ab1[8192];
    __shared__ int S[64 * 10];

    const int blk = blockIdx.x;
    int deg = 0;
#pragma unroll
    for (int d = 1; d <= 10; ++d) if (blk >= TS[d]) deg = d;
    const int tile = blk - TS[deg];

    switch (deg) {
        case 0:  gc1_body<0 >(tile, Ab0, Ab1, S, B, bg, bb, bm, bv, nullptr);   break;
        case 1:  gc1_body<1 >(tile, Ab0, Ab1, S, B, bg, bb, bm, bv, adj.p[0]);  break;
        case 2:  gc1_body<2 >(tile, Ab0, Ab1, S, B, bg, bb, bm, bv, adj.p[1]);  break;
        case 3:  gc1_body<3 >(tile, Ab0, Ab1, S, B, bg, bb, bm, bv, adj.p[2]);  break;
        case 4:  gc1_body<4 >(tile, Ab0, Ab1, S, B, bg, bb, bm, bv, adj.p[3]);  break;
        case 5:  gc1_body<5 >(tile, Ab0, Ab1, S, B, bg, bb, bm, bv, adj.p[4]);  break;
        case 6:  gc1_body<6 >(tile, Ab0, Ab1, S, B, bg, bb, bm, bv, adj.p[5]);  break;
        case 7:  gc1_body<7 >(tile, Ab0, Ab1, S, B, bg, bb, bm, bv, adj.p[6]);  break;
        case 8:  gc1_body<8 >(tile, Ab0, Ab1, S, B, bg, bb, bm, bv, adj.p[7]);  break;
        case 9:  gc1_body<9 >(tile, Ab0, Ab1, S, B, bg, bb, bm, bv, adj.p[8]);  break;
        case 10: gc1_body<10>(tile, Ab0, Ab1, S, B, bg, bb, bm, bv, adj.p[9]);  break;
    }
}

// ---------------- K2: deterministic segment sum/max partials ----------------
__global__ __launch_bounds__(128) void k_seg(const int* __restrict__ memb)
{
    const int b = blockIdx.x % NB;
    const int s = blockIdx.x / NB;
    const int aLo = s * (200000 / NSEG);
    const int aHi = aLo + (200000 / NSEG);
    const int wave = threadIdx.x >> 6;
    const int lane = threadIdx.x & 63;

    __shared__ int q[2][256];
    __shared__ int qn[2];
    int* myq = q[wave];
    int nq = 0;

    for (int base = aLo + wave * 64; base < aHi; base += 128) {
        const int a = base + lane;
        const bool m = (a < aHi) && (memb[a] == b);
        const unsigned long long bal = __ballot(m);
        if (m) {
            const int pos = __popcll(bal & ((1ull << lane) - 1ull));
            if (nq + pos < 256) myq[nq + pos] = a;
        }
        nq += __popcll(bal);
    }
    if (lane == 0) qn[wave] = min(nq, 256);
    __syncthreads();

    const int c = threadIdx.x;  // col 0..127
    float sum = 0.f, mx = -FLT_MAX;
#pragma unroll
    for (int w2 = 0; w2 < 2; ++w2) {
        const int n = qn[w2];
        for (int i = 0; i < n; ++i) {
            const float v = g_bn1[(size_t)q[w2][i] * HID + c];
            sum += v;
            mx = fmaxf(mx, v);
        }
    }
    float* pd = g_part + (size_t)(s * NB + b) * 256;
    pd[c] = sum;
    pd[128 + c] = mx;
}

// ---------------- K3: reduce partials, tanh, dense [256,24], softmax pairs ----------------
__global__ __launch_bounds__(256) void k_final(const float* __restrict__ W2,
                                               const float* __restrict__ b2,
                                               float* __restrict__ out)
{
    const int b = blockIdx.x;
    const int t = threadIdx.x;
    __shared__ float ro[256];
    __shared__ float lg[24];

    {
        float v;
        if (t < 128) {
            float sv = 0.f;
            for (int s = 0; s < NSEG; ++s) sv += g_part[(size_t)(s * NB + b) * 256 + t];
            v = sv;
        } else {
            float mv = -FLT_MAX;
            for (int s = 0; s < NSEG; ++s) mv = fmaxf(mv, g_part[(size_t)(s * NB + b) * 256 + t]);
            v = mv;
        }
        ro[t] = tanhf(v);
    }
    __syncthreads();
    if (t < 24) {
        float acc = b2[t];
        for (int c = 0; c < 256; ++c) acc = fmaf(ro[c], W2[c * 24 + t], acc);
        lg[t] = acc;
    }
    __syncthreads();
    if (t < NT) {
        const float l0 = lg[2 * t], l1 = lg[2 * t + 1];
        const float m = fmaxf(l0, l1);
        const float e0 = expf(l0 - m), e1 = expf(l1 - m);
        const float inv = 1.f / (e0 + e1);
        out[b * 24 + 2 * t]     = e0 * inv;
        out[b * 24 + 2 * t + 1] = e1 * inv;
    }
}

extern "C" void kernel_launch(void* const* d_in, const int* in_sizes, int n_in,
                              void* d_out, int out_size, void* d_ws, size_t ws_size,
                              hipStream_t stream) {
    const float* X    = (const float*)d_in[0];
    const int*   memb = (const int*)d_in[2];
    AdjPtrs adj;
    for (int d = 0; d < 10; ++d) adj.p[d] = (const int*)d_in[3 + d];
    const float* W1 = (const float*)d_in[13];
    const float* B1 = (const float*)d_in[14];
    const float* bg = (const float*)d_in[17];
    const float* bb = (const float*)d_in[18];
    const float* bm = (const float*)d_in[19];
    const float* bv = (const float*)d_in[20];
    const float* W2 = (const float*)d_in[31];
    const float* b2 = (const float*)d_in[32];
    float* out = (float*)d_out;

    k_wconv<<<440, 64, 0, stream>>>(W1);
    k_xpad<<<3125, 256, 0, stream>>>(X);
    k_gc1<<<3129, 512, 0, stream>>>(B1, bg, bb, bm, bv, adj);
    k_seg<<<NSEG * NB, 128, 0, stream>>>(memb);
    k_final<<<NB, 256, 0, stream>>>(W2, b2, out);
}

// Round 6
// 167.612 us; speedup vs baseline: 1.4414x; 1.1018x over previous
//
#include <hip/hip_runtime.h>
#include <hip/hip_bf16.h>
#include <float.h>

#define NF 75
#define HID 128
#define NB 50
#define NT 12
#define BN_EPS 1e-3f
#define NSEG 64
#define ROWB 656   // LDS A-tile row stride in bytes (164 dwords == 4 mod 32 -> bank rotation)

typedef __attribute__((ext_vector_type(8))) short short8;
typedef __attribute__((ext_vector_type(4))) float f32x4;

// Static device scratch. Fully written before read on every launch.
__device__ float g_bn1[(size_t)200000 * HID];            // 102.4 MB
__device__ float g_xp[(size_t)200000 * 80];              // padded X, 64 MB
__device__ float g_part[NSEG * NB * 256];                // segment partials
__device__ unsigned short g_wfrag[11 * 5 * 8 * 64 * 16]; // frag-ordered W, hi/lo bf16

struct AdjPtrs { const int* p[10]; };

__device__ __forceinline__ unsigned short f2bf(float x) {
    union { float f; unsigned u; } a; a.f = x;
    unsigned r = a.u + 0x7fffu + ((a.u >> 16) & 1u);   // RTNE
    return (unsigned short)(r >> 16);
}
__device__ __forceinline__ float bf2f(unsigned short h) {
    union { unsigned u; float f; } a; a.u = ((unsigned)h) << 16; return a.f;
}
__device__ __forceinline__ float fast_tanh(float x) {
    float e = __expf(2.f * x);
    return 1.f - 2.f / (e + 1.f);
}

__device__ constexpr int DS_[12] = {0,1000,20000,60000,120000,170000,185000,193000,197000,199000,199700,200000};

// ---------------- K_xpad: X[200000][75] -> g_xp[200000][80], zero-padded ----------------
__global__ __launch_bounds__(256) void k_xpad(const float* __restrict__ X) {
    __shared__ float T[64 * 75];
    const float4* src = (const float4*)(X + (size_t)blockIdx.x * 4800);
    for (int i = threadIdx.x; i < 1200; i += 256)
        *(float4*)&T[i * 4] = src[i];
    __syncthreads();
    float4* dst = (float4*)(g_xp + (size_t)blockIdx.x * 5120);
    for (int o = threadIdx.x; o < 1280; o += 256) {
        const int row = o / 20, f0 = (o % 20) * 4;
        float4 r;
        r.x = (f0 + 0 < 75) ? T[row * 75 + f0 + 0] : 0.f;
        r.y = (f0 + 1 < 75) ? T[row * 75 + f0 + 1] : 0.f;
        r.z = (f0 + 2 < 75) ? T[row * 75 + f0 + 2] : 0.f;
        r.w = (f0 + 3 < 75) ? T[row * 75 + f0 + 3] : 0.f;
        dst[o] = r;
    }
}

// ---------------- K0: W -> fragment-ordered bf16 hi/lo ----------------
// Kcat per degree: k in [0,75) rel rows, [80,155) self rows, else 0. deg0: self only.
__global__ __launch_bounds__(64) void k_wconv(const float* __restrict__ W) {
    const int id = blockIdx.x;                 // deg*40 + kt*8 + nt
    const int deg = id / 40, kt = (id / 8) % 5, nt = id % 8;
    const int lane = threadIdx.x;
    const int c  = nt * 16 + (lane & 15);
    const int kb = kt * 32 + (lane >> 4) * 8;
    unsigned short hs[8], ls[8];
#pragma unroll
    for (int i = 0; i < 8; ++i) {
        const int k = kb + i;
        float v = 0.f;
        if (deg > 0) {
            if (k < 75)                  v = W[(size_t)(2 * (deg - 1)) * NF * HID + (size_t)k * HID + c];
            else if (k >= 80 && k < 155) v = W[(size_t)(2 * (deg - 1) + 1) * NF * HID + (size_t)(k - 80) * HID + c];
        } else {
            if (k >= 80 && k < 155)      v = W[(size_t)20 * NF * HID + (size_t)(k - 80) * HID + c];
        }
        const unsigned short h = f2bf(v);
        hs[i] = h;
        ls[i] = f2bf(v - bf2f(h));
    }
    unsigned short* dst = g_wfrag + ((size_t)id * 64 + lane) * 16;
#pragma unroll
    for (int i = 0; i < 8; ++i) { dst[i] = hs[i]; dst[8 + i] = ls[i]; }
}

// ---------------- K1: gc1 via MFMA, one-shot staged A-tile ----------------
// 512 threads = 8 waves. Staging: thread (srow=tid&63, wid=tid>>6) fills k-chunk
// k0 = j*32 + wid*4 for j=0..4 (rel gather if k0<80, self load else).
// Row layout (ROWB=656B): kt*128 + g*32 + {hi 16B | lo 16B}; no XOR (stride rotates banks).
// MFMA: wave wid owns cols [wid*16,wid*16+16); A row=(l&15)+16m, k=(l>>4)*8+i.
template<int DEG>
__device__ __forceinline__ void gc1_body(
    int tile, char* __restrict__ A, int* __restrict__ S,
    const float* __restrict__ B,
    const float* __restrict__ bg, const float* __restrict__ bb,
    const float* __restrict__ bm, const float* __restrict__ bv,
    const int* __restrict__ adjBase)
{
    const int dStart = DS_[DEG], dEnd = DS_[DEG + 1];
    const int atom0  = dStart + tile * 64;
    const int nA     = min(64, dEnd - atom0);
    const int tid    = threadIdx.x;
    const int lane   = tid & 63;
    const int wid    = tid >> 6;

    if (DEG > 0) {
        for (int idx = tid; idx < 64 * DEG; idx += 512) {
            const int a = idx / DEG;
            S[idx] = (a < nA) ? adjBase[(size_t)(atom0 + a - dStart) * DEG + (idx - a * DEG)] : 0;
        }
        __syncthreads();
    }

    // own adjacency row -> registers
    int adjr[DEG > 0 ? DEG : 1];
    if (DEG > 0) {
#pragma unroll
        for (int j = 0; j < DEG; ++j) adjr[j] = S[lane * DEG + j];
    }

    const int srow = lane;
    char* wbase = A + srow * ROWB + (wid >> 1) * 32 + (wid & 1) * 8;

#pragma unroll 1
    for (int j = 0; j < 5; ++j) {
        const int k0 = j * 32 + wid * 4;
        float4 v; v.x = v.y = v.z = v.w = 0.f;
        if (srow < nA) {
            if (k0 >= 80) {
                v = *(const float4*)(g_xp + (size_t)(atom0 + srow) * 80 + (k0 - 80));
            } else if (DEG > 0) {
#pragma unroll
                for (int j2 = 0; j2 < DEG; ++j2) {
                    const float4 t = *(const float4*)(g_xp + (size_t)adjr[j2] * 80 + k0);
                    v.x += t.x; v.y += t.y; v.z += t.z; v.w += t.w;
                }
            }
        }
        const float vv[4] = {v.x, v.y, v.z, v.w};
        unsigned long long hp = 0, lp = 0;
#pragma unroll
        for (int ii = 0; ii < 4; ++ii) {
            const unsigned short h = f2bf(vv[ii]);
            const unsigned short l = f2bf(vv[ii] - bf2f(h));
            hp |= (unsigned long long)h << (16 * ii);
            lp |= (unsigned long long)l << (16 * ii);
        }
        *(unsigned long long*)(wbase + j * 128)      = hp;
        *(unsigned long long*)(wbase + j * 128 + 16) = lp;
    }
    __syncthreads();

    f32x4 acc[4] = {};
    const int gk = lane >> 4;
    const int kt0 = (DEG == 0) ? 2 : 0;
#pragma unroll
    for (int kt = kt0; kt < 5; ++kt) {
        const unsigned short* wp = g_wfrag + ((size_t)(((DEG * 5 + kt) * 8 + wid) * 64 + lane)) * 16;
        const short8 wh = *(const short8*)wp;
        const short8 wl = *(const short8*)(wp + 8);
#pragma unroll
        for (int m = 0; m < 4; ++m) {
            const char* ab = A + (m * 16 + (lane & 15)) * ROWB + kt * 128 + gk * 32;
            const short8 ah = *(const short8*)ab;
            const short8 al = *(const short8*)(ab + 16);
            acc[m] = __builtin_amdgcn_mfma_f32_16x16x32_bf16(ah, wh, acc[m], 0, 0, 0);
            acc[m] = __builtin_amdgcn_mfma_f32_16x16x32_bf16(al, wh, acc[m], 0, 0, 0);
            acc[m] = __builtin_amdgcn_mfma_f32_16x16x32_bf16(ah, wl, acc[m], 0, 0, 0);
        }
    }

    const int col = wid * 16 + (lane & 15);
    const float bsum = (DEG > 0)
        ? (B[(size_t)(2 * (DEG - 1)) * HID + col] + B[(size_t)(2 * (DEG - 1) + 1) * HID + col])
        : B[(size_t)20 * HID + col];
    const float s  = bg[col] * rsqrtf(bv[col] + BN_EPS);
    const float sh = bb[col] - bm[col] * s;
#pragma unroll
    for (int m = 0; m < 4; ++m) {
#pragma unroll
        for (int j = 0; j < 4; ++j) {
            const int r = m * 16 + (lane >> 4) * 4 + j;
            if (r < nA)
                g_bn1[(size_t)(atom0 + r) * HID + col] = fast_tanh(acc[m][j] + bsum) * s + sh;
        }
    }
}

__global__ __launch_bounds__(512, 4) void k_gc1(
    const float* __restrict__ B,
    const float* __restrict__ bg, const float* __restrict__ bb,
    const float* __restrict__ bm, const float* __restrict__ bv,
    AdjPtrs adj)
{
    // heavy-first: deg 10,9,...,1,0
    constexpr int TSH[12]   = {0,5,16,48,111,236,471,1253,2191,2816,3113,3129};
    constexpr int DEGORD[11] = {10,9,8,7,6,5,4,3,2,1,0};
    __shared__ __align__(16) char A[64 * ROWB];   // 41.98 KB
    __shared__ int S[64 * 10];                    // 2.5 KB

    const int blk = blockIdx.x;
    int seg = 0;
#pragma unroll
    for (int s = 1; s <= 10; ++s) if (blk >= TSH[s]) seg = s;
    const int deg  = DEGORD[seg];
    const int tile = blk - TSH[seg];

    switch (deg) {
        case 0:  gc1_body<0 >(tile, A, S, B, bg, bb, bm, bv, nullptr);   break;
        case 1:  gc1_body<1 >(tile, A, S, B, bg, bb, bm, bv, adj.p[0]);  break;
        case 2:  gc1_body<2 >(tile, A, S, B, bg, bb, bm, bv, adj.p[1]);  break;
        case 3:  gc1_body<3 >(tile, A, S, B, bg, bb, bm, bv, adj.p[2]);  break;
        case 4:  gc1_body<4 >(tile, A, S, B, bg, bb, bm, bv, adj.p[3]);  break;
        case 5:  gc1_body<5 >(tile, A, S, B, bg, bb, bm, bv, adj.p[4]);  break;
        case 6:  gc1_body<6 >(tile, A, S, B, bg, bb, bm, bv, adj.p[5]);  break;
        case 7:  gc1_body<7 >(tile, A, S, B, bg, bb, bm, bv, adj.p[6]);  break;
        case 8:  gc1_body<8 >(tile, A, S, B, bg, bb, bm, bv, adj.p[7]);  break;
        case 9:  gc1_body<9 >(tile, A, S, B, bg, bb, bm, bv, adj.p[8]);  break;
        case 10: gc1_body<10>(tile, A, S, B, bg, bb, bm, bv, adj.p[9]);  break;
    }
}

// ---------------- K2: deterministic segment sum/max partials ----------------
__global__ __launch_bounds__(128) void k_seg(const int* __restrict__ memb)
{
    const int b = blockIdx.x % NB;
    const int s = blockIdx.x / NB;
    const int aLo = s * (200000 / NSEG);
    const int aHi = aLo + (200000 / NSEG);
    const int wave = threadIdx.x >> 6;
    const int lane = threadIdx.x & 63;

    __shared__ int q[2][256];
    __shared__ int qn[2];
    int* myq = q[wave];
    int nq = 0;

    for (int base = aLo + wave * 64; base < aHi; base += 128) {
        const int a = base + lane;
        const bool m = (a < aHi) && (memb[a] == b);
        const unsigned long long bal = __ballot(m);
        if (m) {
            const int pos = __popcll(bal & ((1ull << lane) - 1ull));
            if (nq + pos < 256) myq[nq + pos] = a;
        }
        nq += __popcll(bal);
    }
    if (lane == 0) qn[wave] = min(nq, 256);
    __syncthreads();

    const int c = threadIdx.x;  // col 0..127
    float sum = 0.f, mx = -FLT_MAX;
#pragma unroll
    for (int w2 = 0; w2 < 2; ++w2) {
        const int n = qn[w2];
        for (int i = 0; i < n; ++i) {
            const float v = g_bn1[(size_t)q[w2][i] * HID + c];
            sum += v;
            mx = fmaxf(mx, v);
        }
    }
    float* pd = g_part + (size_t)(s * NB + b) * 256;
    pd[c] = sum;
    pd[128 + c] = mx;
}

// ---------------- K3: reduce partials, tanh, dense [256,24], softmax pairs ----------------
__global__ __launch_bounds__(256) void k_final(const float* __restrict__ W2,
                                               const float* __restrict__ b2,
                                               float* __restrict__ out)
{
    const int b = blockIdx.x;
    const int t = threadIdx.x;
    __shared__ float ro[256];
    __shared__ float lg[24];

    {
        float v;
        if (t < 128) {
            float sv = 0.f;
            for (int s = 0; s < NSEG; ++s) sv += g_part[(size_t)(s * NB + b) * 256 + t];
            v = sv;
        } else {
            float mv = -FLT_MAX;
            for (int s = 0; s < NSEG; ++s) mv = fmaxf(mv, g_part[(size_t)(s * NB + b) * 256 + t]);
            v = mv;
        }
        ro[t] = tanhf(v);
    }
    __syncthreads();
    if (t < 24) {
        float acc = b2[t];
        for (int c = 0; c < 256; ++c) acc = fmaf(ro[c], W2[c * 24 + t], acc);
        lg[t] = acc;
    }
    __syncthreads();
    if (t < NT) {
        const float l0 = lg[2 * t], l1 = lg[2 * t + 1];
        const float m = fmaxf(l0, l1);
        const float e0 = expf(l0 - m), e1 = expf(l1 - m);
        const float inv = 1.f / (e0 + e1);
        out[b * 24 + 2 * t]     = e0 * inv;
        out[b * 24 + 2 * t + 1] = e1 * inv;
    }
}

extern "C" void kernel_launch(void* const* d_in, const int* in_sizes, int n_in,
                              void* d_out, int out_size, void* d_ws, size_t ws_size,
                              hipStream_t stream) {
    const float* X    = (const float*)d_in[0];
    const int*   memb = (const int*)d_in[2];
    AdjPtrs adj;
    for (int d = 0; d < 10; ++d) adj.p[d] = (const int*)d_in[3 + d];
    const float* W1 = (const float*)d_in[13];
    const float* B1 = (const float*)d_in[14];
    const float* bg = (const float*)d_in[17];
    const float* bb = (const float*)d_in[18];
    const float* bm = (const float*)d_in[19];
    const float* bv = (const float*)d_in[20];
    const float* W2 = (const float*)d_in[31];
    const float* b2 = (const float*)d_in[32];
    float* out = (float*)d_out;

    k_wconv<<<440, 64, 0, stream>>>(W1);
    k_xpad<<<3125, 256, 0, stream>>>(X);
    k_gc1<<<3129, 512, 0, stream>>>(B1, bg, bb, bm, bv, adj);
    k_seg<<<NSEG * NB, 128, 0, stream>>>(memb);
    k_final<<<NB, 256, 0, stream>>>(W2, b2, out);
}